// Round 12
// baseline (82.505 us; speedup 1.0000x reference)
//
#include <hip/hip_runtime.h>

typedef __attribute__((ext_vector_type(8))) _Float16 f16x8;
typedef __attribute__((ext_vector_type(4))) _Float16 f16x4;
typedef __attribute__((ext_vector_type(4))) float   f32x4;

#define BATCH 16384
#define NFEAT 512
#define NCLS  1000
#define NLEAF 256
#define NINT  255
#define LDP   72    // staging LDS row stride (f16), 144B: 16B-aligned, 2-way banks
#define PSTR  257   // P LDS row stride (f32), odd: 2-way max on sigmoid writes

// ---- convert gate_w (255x512) -> f16 padded to 256x512 (row 255 = 0) ----
__global__ __launch_bounds__(256) void cvt_gw(const float4* __restrict__ in,
                                              f16x4* __restrict__ out) {
  int i = blockIdx.x * 256 + threadIdx.x;
  int row = i >> 7;
  f16x4 o;
  if (row < NINT) {
    float4 v = in[i];
    o[0] = (_Float16)v.x; o[1] = (_Float16)v.y;
    o[2] = (_Float16)v.z; o[3] = (_Float16)v.w;
  } else {
    o[0] = o[1] = o[2] = o[3] = (_Float16)0.f;
  }
  out[i] = o;
}

// ---- softmax of leaf_logits rows -> distF in MFMA-fragment-swizzled layout ----
// (class c, leaf l) at ((c>>4)*8 + (l>>5))*512 + ((l>>3&3)*16 + (c&15))*8 + (l&7)
__global__ __launch_bounds__(256) void softmax_t(const float* __restrict__ L,
                                                 _Float16* __restrict__ distF) {
  __shared__ float red[4];
  const int l = blockIdx.x, t = threadIdx.x;
  const int wave = t >> 6, lane = t & 63;
  const int kt = l >> 5, lhi_l = (l >> 3) & 3, jj = l & 7;
  float v[4];
  const bool live = t < 250;
  if (live) {
    float4 f = *(const float4*)&L[(size_t)l * NCLS + t * 4];
    v[0] = f.x; v[1] = f.y; v[2] = f.z; v[3] = f.w;
  } else {
    v[0] = v[1] = v[2] = v[3] = -1e30f;
  }
  float mx = fmaxf(fmaxf(v[0], v[1]), fmaxf(v[2], v[3]));
#pragma unroll
  for (int s = 32; s; s >>= 1) mx = fmaxf(mx, __shfl_xor(mx, s));
  if (lane == 0) red[wave] = mx;
  __syncthreads();
  mx = fmaxf(fmaxf(red[0], red[1]), fmaxf(red[2], red[3]));
  __syncthreads();
  float e[4], sum = 0.f;
#pragma unroll
  for (int i = 0; i < 4; ++i) { e[i] = __expf(v[i] - mx); sum += e[i]; }
  if (!live) { e[0] = e[1] = e[2] = e[3] = 0.f; sum = 0.f; }
#pragma unroll
  for (int s = 32; s; s >>= 1) sum += __shfl_xor(sum, s);
  if (lane == 0) red[wave] = sum;
  __syncthreads();
  sum = red[0] + red[1] + red[2] + red[3];
  float inv = 1.f / sum;
#pragma unroll
  for (int i = 0; i < 4; ++i) {
    int c = t * 4 + i;
    float val = live ? e[i] * inv : 0.f;
    int c16 = c >> 4, ln = c & 15;
    size_t idx = (((size_t)(c16 * 8 + kt)) * 64 + lhi_l * 16 + ln) * 8 + jj;
    distF[idx] = (_Float16)val;
  }
}

// ---- fused: gemm1 + sigmoid + tree + gemm2 ----
// BM=64, 256 blocks (1/CU), 512 threads (8 waves).
// 1-deep phase-1 prefetch (R4-proven live set ~90 VGPR -> no spills anywhere).
__global__ __launch_bounds__(512, 2)
void fused(const float* __restrict__ x, const _Float16* __restrict__ gwh,
           const float* __restrict__ gb, const _Float16* __restrict__ distF,
           float* __restrict__ out) {
  __shared__ union {
    struct { _Float16 A[64 * LDP]; _Float16 B[256 * LDP]; } s;  // 46,080 B
    float P[64 * PSTR];                                         // 65,792 B
  } sm;
  __shared__ _Float16 muF[32 * 512];                            // 32,768 B, fragment layout

  const int tid  = threadIdx.x;
  const int wave = tid >> 6, lane = tid & 63;
  const int ln15 = lane & 15, lhi = lane >> 4;
  const int wr = wave >> 2, wc = wave & 3;      // phase1: 2x4 waves, 32r x 64c
  const int r0 = blockIdx.x * 64;

  float bias_[4];
#pragma unroll
  for (int n = 0; n < 4; ++n) {
    int col = wc * 64 + n * 16 + ln15;
    bias_[n] = (col < NINT) ? gb[col] : 0.f;
  }

  // ---------------- phase 1: logits = x @ gwh^T (1-deep reg prefetch, R4-proven) ----------------
  f32x4 acc1[2][4] = {};
  const int arow = tid >> 4, acol = (tid & 15) * 4;
  const int brow = tid >> 3, bcol = (tid & 7) * 8;

  float4 pa, pa2;
  uint4  pb[4];

#define P1_LOAD(k0)                                                              \
  {                                                                              \
    pa  = *(const float4*)&x[(size_t)(r0 + arow) * NFEAT + (k0) + acol];         \
    pa2 = *(const float4*)&x[(size_t)(r0 + 32 + arow) * NFEAT + (k0) + acol];    \
    _Pragma("unroll")                                                            \
    for (int i = 0; i < 4; ++i)                                                  \
      pb[i] = *(const uint4*)&gwh[(size_t)(i * 64 + brow) * NFEAT + (k0) + bcol];\
  }
#define P1_WRITE()                                                               \
  {                                                                              \
    f16x4 h;                                                                     \
    h[0] = (_Float16)pa.x; h[1] = (_Float16)pa.y;                                \
    h[2] = (_Float16)pa.z; h[3] = (_Float16)pa.w;                                \
    *(f16x4*)&sm.s.A[arow * LDP + acol] = h;                                     \
    h[0] = (_Float16)pa2.x; h[1] = (_Float16)pa2.y;                              \
    h[2] = (_Float16)pa2.z; h[3] = (_Float16)pa2.w;                              \
    *(f16x4*)&sm.s.A[(32 + arow) * LDP + acol] = h;                              \
    _Pragma("unroll")                                                            \
    for (int i = 0; i < 4; ++i)                                                  \
      *(uint4*)&sm.s.B[(i * 64 + brow) * LDP + bcol] = pb[i];                    \
  }

  P1_LOAD(0);
  for (int k = 0; k < NFEAT / 64; ++k) {
    P1_WRITE();                      // waits on in-flight loads (vmcnt)
    __syncthreads();
    if (k < NFEAT / 64 - 1) P1_LOAD((k + 1) * 64);   // next loads fly over MFMA
#pragma unroll
    for (int kk = 0; kk < 2; ++kk) {
      f16x8 a[2], b[4];
#pragma unroll
      for (int m = 0; m < 2; ++m)
        a[m] = *(const f16x8*)&sm.s.A[(wr * 32 + m * 16 + ln15) * LDP + kk * 32 + lhi * 8];
#pragma unroll
      for (int n = 0; n < 4; ++n)
        b[n] = *(const f16x8*)&sm.s.B[(wc * 64 + n * 16 + ln15) * LDP + kk * 32 + lhi * 8];
#pragma unroll
      for (int m = 0; m < 2; ++m)
#pragma unroll
        for (int n = 0; n < 4; ++n)
          acc1[m][n] = __builtin_amdgcn_mfma_f32_16x16x32_f16(a[m], b[n], acc1[m][n], 0, 0, 0);
    }
    __syncthreads();
  }

  // ---------------- phase 2a: sigmoid -> P (LDS, stride 257) ----------------
#pragma unroll
  for (int m = 0; m < 2; ++m)
#pragma unroll
    for (int n = 0; n < 4; ++n) {
      int col = wc * 64 + n * 16 + ln15;
#pragma unroll
      for (int j = 0; j < 4; ++j) {
        int rl = wr * 32 + m * 16 + lhi * 4 + j;
        float v = acc1[m][n][j] + bias_[n];
        sm.P[rl * PSTR + col] = 1.f / (1.f + __expf(-v));
      }
    }
  __syncthreads();

  // ---------------- phase 2b: tree product -> muF (fragment layout) ----------------
  const int lf   = lane * 4;
  const int g_hi = lane >> 3;            // leaf>>5
  const int sub  = ((lane >> 1) & 3) * 16;
  const int j4   = (lane & 1) * 4;
#pragma unroll
  for (int rr = 0; rr < 8; ++rr) {
    int row = wave * 8 + rr;
    const float* p = &sm.P[row * PSTR];
    float pre = 1.f;
#pragma unroll
    for (int d = 0; d < 6; ++d) {
      int node = (1 << d) - 1 + (lf >> (8 - d));
      int bit  = (lf >> (7 - d)) & 1;
      float g = p[node];
      pre *= bit ? g : (1.f - g);
    }
    float g6  = p[63 + lane];
    float g7a = p[127 + 2 * lane];
    float g7b = p[128 + 2 * lane];
    f16x4 o;
    o[0] = (_Float16)(pre * (1.f - g6) * (1.f - g7a));
    o[1] = (_Float16)(pre * (1.f - g6) * g7a);
    o[2] = (_Float16)(pre * g6 * (1.f - g7b));
    o[3] = (_Float16)(pre * g6 * g7b);
    *(f16x4*)&muF[(((row >> 4) * 8 + g_hi) * 64 + sub + (row & 15)) * 8 + j4] = o;
  }
  __syncthreads();

  // ---------------- phase 3: out = mu @ dist^T, one 16-col group at a time ----------------
  const int wr2 = wave >> 2, wc2 = wave & 3;
  const int rbase = r0 + wr2 * 32 + lhi * 4;
  for (int ct = 0; ct < 8; ++ct) {
#pragma unroll
    for (int h = 0; h < 2; ++h) {
      const int c16 = ct * 8 + wc2 * 2 + h;
      f16x8 bb[8];
#pragma unroll
      for (int kk = 0; kk < 8; ++kk)   // 64 lanes x 16B = 1KB contiguous per load
        bb[kk] = *(const f16x8*)&distF[(((size_t)c16 * 8 + kk) * 64 + lane) * 8];
      f32x4 acc0 = {}, acc1v = {};
#pragma unroll
      for (int kk = 0; kk < 8; ++kk) {
        f16x8 a0 = *(const f16x8*)&muF[(((wr2 * 2    ) * 8 + kk) * 64 + lane) * 8];
        f16x8 a1 = *(const f16x8*)&muF[(((wr2 * 2 + 1) * 8 + kk) * 64 + lane) * 8];
        acc0  = __builtin_amdgcn_mfma_f32_16x16x32_f16(a0, bb[kk], acc0, 0, 0, 0);
        acc1v = __builtin_amdgcn_mfma_f32_16x16x32_f16(a1, bb[kk], acc1v, 0, 0, 0);
      }
      const int col = c16 * 16 + ln15;
      if (col < NCLS) {
#pragma unroll
        for (int j = 0; j < 4; ++j) {
          out[(size_t)(rbase + j) * NCLS + col]      = acc0[j];
          out[(size_t)(rbase + 16 + j) * NCLS + col] = acc1v[j];
        }
      }
    }
  }
#undef P1_LOAD
#undef P1_WRITE
}

extern "C" void kernel_launch(void* const* d_in, const int* in_sizes, int n_in,
                              void* d_out, int out_size, void* d_ws, size_t ws_size,
                              hipStream_t stream) {
  const float* x  = (const float*)d_in[0];   // 16384x512
  const float* gw = (const float*)d_in[1];   // 255x512
  const float* gb = (const float*)d_in[2];   // 255
  const float* ll = (const float*)d_in[3];   // 256x1000
  float* out = (float*)d_out;                // 16384x1000
  char* ws = (char*)d_ws;

  _Float16* gwh   = (_Float16*)(ws);            // 262,144 B
  _Float16* distF = (_Float16*)(ws + 262144);   // 524,288 B (1024x256 swizzled)

  cvt_gw   <<<128, 256, 0, stream>>>((const float4*)gw, (f16x4*)gwh);
  softmax_t<<<256, 256, 0, stream>>>(ll, distF);
  fused    <<<BATCH / 64, 512, 0, stream>>>(x, gwh, gb, distF, out);
}